// Round 11
// baseline (185.647 us; speedup 1.0000x reference)
//
#include <hip/hip_runtime.h>
#include <stdint.h>

#define B_ 4
#define S_ 2048
#define D_ 768
#define U_ 768

typedef __bf16 bf16x8 __attribute__((ext_vector_type(8)));
typedef float f32x4 __attribute__((ext_vector_type(4)));

#define AS1 __attribute__((address_space(1)))
#define AS3 __attribute__((address_space(3)))

#define BAR() __builtin_amdgcn_s_barrier()
#define WAITV8() asm volatile("s_waitcnt vmcnt(8)" ::: "memory")
#define WAITV6() asm volatile("s_waitcnt vmcnt(6)" ::: "memory")
#define WAITV0() asm volatile("s_waitcnt vmcnt(0)" ::: "memory")
#define PRIO(x) __builtin_amdgcn_s_setprio(x)

__device__ __forceinline__ ushort f2bf(float f) {
    union { float f; uint32_t u; } v; v.f = f;
    uint32_t r = v.u + 0x7fffu + ((v.u >> 16) & 1u);
    return (ushort)(r >> 16);
}

__device__ __forceinline__ float bflo(uint32_t u) {
    union { uint32_t u; float f; } v; v.u = u << 16; return v.f;
}
__device__ __forceinline__ float bfhi(uint32_t u) {
    union { uint32_t u; float f; } v; v.u = u & 0xffff0000u; return v.f;
}

__device__ __forceinline__ void gload_lds16(const void* gp, void* lp) {
    // width-16 global->LDS: HW scatters to (wave-uniform lds base) + lane*16
    __builtin_amdgcn_global_load_lds((AS1 void*)gp, (AS3 void*)lp, 16, 0, 0);
}

// ============================================================================
// 256 x (64*NF) 8-phase pipelined GEMM (BK=64, 8 waves 2Mx4N, counted vmcnt,
// XOR-swizzled LDS, setprio).  C = A[M,K] @ Bt[N,K]^T.   NF in {4, 6}.
// NF=4 (BN=256): identical to the proven r10 structure (vmcnt(6)).
// NF=6 (BN=384): B staged in 3 halves (p1,p2,p3); tile-end vmcnt(8) —
//   in-flight = {B0,B1,B2,A-h0}(t+2); A-h1(t+1) issued before them => landed.
//   WAR discipline identical (>=2 barriers between read-issue and DMA).
// MODE 0: bf16 row-major out (value*scale).
// MODE 1 (NF=4 only): bf16 -> Vt[B][U][S] via LDS-transposed coalesced stores.
// MODE 2: f32 * scale.
// LDS: sA[2][256*64] + sB[2][BN*64] bf16 = 128 KiB (NF=4) / 160 KiB (NF=6).
// ============================================================================
template <int MODE, int NF>
__device__ __forceinline__ void gemmN(
    ushort* sm,
    const ushort* __restrict__ Ag, int lda,
    const ushort* __restrict__ Btg, int ldb,
    void* __restrict__ Cp, int ldc, int Kd, float scale,
    int ty, int tx)
{
    constexpr int ABUF = 256 * 64;
    constexpr int BBUF = NF * 64 * 64;   // BN*64 elems
    constexpr int BN = NF * 64;
    ushort* sA = sm;
    ushort* sB = sm + 2 * ABUF;

    const int tid = threadIdx.x;
    const int l = tid & 63, w = tid >> 6;
    const int lr = l & 15, lg = l >> 4;
    const int wm = w >> 2, wn = w & 3;
    const int M0 = ty * 256, N0 = tx * BN;

    f32x4 acc[8][NF];
#pragma unroll
    for (int m = 0; m < 8; ++m)
#pragma unroll
        for (int n = 0; n < NF; ++n)
            acc[m][n] = (f32x4){0.f, 0.f, 0.f, 0.f};

    const int NT = Kd >> 6;

    auto STA = [&](int buf, int qp, int kt) {
#pragma unroll
        for (int j = 0; j < 2; ++j) {
            int q = qp + j;
            int r0 = (w < 4) ? (q * 32 + w * 8) : (128 + q * 32 + (w - 4) * 8);
            int r = r0 + (l >> 3);
            int lc = ((l & 7) * 16) ^ ((r & 7) << 4);
            gload_lds16(Ag + (size_t)(M0 + r) * lda + kt * 64 + (lc >> 1),
                        sA + buf * ABUF + r0 * 64);
        }
    };
    auto STB = [&](int buf, int h, int kt) {
#pragma unroll
        for (int j = 0; j < 2; ++j) {
            int r0 = h * 128 + j * 64 + w * 8;
            int r = r0 + (l >> 3);
            int lc = ((l & 7) * 16) ^ ((r & 7) << 4);
            gload_lds16(Btg + (size_t)(N0 + r) * ldb + kt * 64 + (lc >> 1),
                        sB + buf * BBUF + r0 * 64);
        }
    };

    bf16x8 afr[2][2], bfr[NF][2];
    auto LDB = [&](int buf) {
#pragma unroll
        for (int nf = 0; nf < NF; ++nf)
#pragma unroll
            for (int ks = 0; ks < 2; ++ks) {
                int r = wn * (16 * NF) + nf * 16 + lr;
                int off = r * 128 + ((ks * 64 + lg * 16) ^ ((r & 7) << 4));
                bfr[nf][ks] = *(const bf16x8*)((const char*)(sB + buf * BBUF) + off);
            }
    };
    auto LDA = [&](int buf, int q) {
#pragma unroll
        for (int j = 0; j < 2; ++j)
#pragma unroll
            for (int ks = 0; ks < 2; ++ks) {
                int r = wm * 128 + (2 * q + j) * 16 + lr;
                int off = r * 128 + ((ks * 64 + lg * 16) ^ ((r & 7) << 4));
                afr[j][ks] = *(const bf16x8*)((const char*)(sA + buf * ABUF) + off);
            }
    };

#define MMQ(Q)                                                                 \
    PRIO(1);                                                                   \
    _Pragma("unroll")                                                          \
    for (int j = 0; j < 2; ++j)                                                \
        _Pragma("unroll")                                                      \
        for (int nf = 0; nf < NF; ++nf)                                        \
            _Pragma("unroll")                                                  \
            for (int ks = 0; ks < 2; ++ks)                                     \
                acc[2 * (Q) + j][nf] = __builtin_amdgcn_mfma_f32_16x16x32_bf16(\
                    afr[j][ks], bfr[nf][ks], acc[2 * (Q) + j][nf], 0, 0, 0);   \
    PRIO(0);

#define WAITN()                                                                \
    do { if constexpr (NF == 6) { WAITV8(); } else { WAITV6(); } } while (0)

    // prologue: tile0 fully + tile1's {all B halves, A-q01}
    STA(0, 0, 0); STA(0, 2, 0);
    STB(0, 0, 0); STB(0, 1, 0);
    if constexpr (NF == 6) STB(0, 2, 0);
    if (NT > 1) {
        STB(1, 0, 1); STB(1, 1, 1);
        if constexpr (NF == 6) STB(1, 2, 1);
        STA(1, 0, 1);
        WAITN();
    } else {
        WAITV0();
    }
    BAR();

    for (int t = 0; t < NT; ++t) {
        const int c = t & 1;
        LDB(c); LDA(c, 0);
        if (t + 1 < NT) STA(c ^ 1, 2, t + 1);
        BAR();
        MMQ(0);
        BAR();
        LDA(c, 1);
        if (t + 2 < NT) STB(c, 0, t + 2);
        BAR();
        MMQ(1);
        BAR();
        LDA(c, 2);
        if (t + 2 < NT) STB(c, 1, t + 2);
        BAR();
        MMQ(2);
        BAR();
        LDA(c, 3);
        if (t + 2 < NT) {
            if constexpr (NF == 6) STB(c, 2, t + 2);
            STA(c, 0, t + 2);
        }
        BAR();
        MMQ(3);
        if (t + 2 < NT) { WAITN(); } else { WAITV0(); }
        BAR();
    }
#undef MMQ
#undef WAITN

    if constexpr (MODE == 1) {
        // ---- LDS-transposed Vt epilogue (coalesced stores), NF=4 only ----
        __syncthreads();               // all GEMM LDS reads complete
        uint32_t* smw = (uint32_t*)sm;
#pragma unroll
        for (int mf = 0; mf < 8; ++mf) {
#pragma unroll
            for (int nf = 0; nf < NF; ++nf) {
                int cc = wn * 64 + nf * 16 + lr;          // local col (u)
                int r0 = wm * 128 + mf * 16 + lg * 4;     // local row, mult 4
                uint32_t d0 = (uint32_t)f2bf(acc[mf][nf][0]) |
                              ((uint32_t)f2bf(acc[mf][nf][1]) << 16);
                uint32_t d1 = (uint32_t)f2bf(acc[mf][nf][2]) |
                              ((uint32_t)f2bf(acc[mf][nf][3]) << 16);
                smw[cc * 129 + (r0 >> 1)] = d0;
                smw[cc * 129 + (r0 >> 1) + 1] = d1;
            }
        }
        __syncthreads();
        const int bb = M0 >> 11;                          // batch (no straddle)
        const int s0 = M0 & 2047;
        const int kd = tid & 127;                         // dword within row
        int u = tid >> 7;                                 // 0..3 start row
#pragma unroll
        for (int it = 0; it < 64; ++it) {
            uint32_t d = smw[u * 129 + kd];
            uint32_t* vrow = (uint32_t*)((ushort*)Cp +
                ((size_t)(bb * U_ + N0 + u)) * S_ + s0);
            vrow[kd] = d;
            u += 4;
        }
        return;
    }

    // epilogue: C/D frag mapping col = lane&15, row = (lane>>4)*4 + i
#pragma unroll
    for (int mf = 0; mf < 8; ++mf) {
#pragma unroll
        for (int nf = 0; nf < NF; ++nf) {
#pragma unroll
            for (int i = 0; i < 4; ++i) {
                int r = M0 + wm * 128 + mf * 16 + lg * 4 + i;
                int c = N0 + wn * (16 * NF) + nf * 16 + lr;
                float v = acc[mf][nf][i];
                if constexpr (MODE == 0) {
                    ((ushort*)Cp)[(size_t)r * ldc + c] = f2bf(v * scale);
                } else {
                    ((float*)Cp)[(size_t)r * ldc + c] = v * scale;
                }
            }
        }
    }
}

// ============================================================================
// Mixed QKV projection, ONE round: 224 blocks = 8 XCD x 28.
//   j < 16 : Q/K at 256x384 (gemmN<.,6>), 128 blocks (32 ty x 2 tx x 2 z)
//   j >= 16: V   at 256x256 MODE 1 (transpose epilogue), 96 blocks
// LDS: 163840 B (NF=6 path); V path uses first 132096 B.
// ============================================================================
__global__ __launch_bounds__(512) void proj_mix_kernel(
    const ushort* __restrict__ xb, const ushort* __restrict__ Wt,
    ushort* __restrict__ Qb, ushort* __restrict__ Kb,
    ushort* __restrict__ Vt, float qscale) {
    extern __shared__ ushort sm[];
    const int b0 = blockIdx.x;                      // 224 = 8 XCD x 28
    const int i = b0 & 7, j = b0 >> 3;
    if (j < 16) {
        int ty = i * 4 + (j >> 2), rem = j & 3;
        int z = rem >> 1, tx = rem & 1;
        if (z == 0)
            gemmN<0, 6>(sm, xb, D_, Wt, D_, Qb, U_, D_, qscale, ty, tx);
        else
            gemmN<0, 6>(sm, xb, D_, Wt + (size_t)U_ * D_, D_, Kb, U_, D_, 1.f, ty, tx);
    } else {
        int j2 = j - 16;
        int ty = i * 4 + j2 / 3, tx = j2 % 3;
        gemmN<1, 4>(sm, xb, D_, Wt + (size_t)2 * U_ * D_, D_, Vt, 0, D_, 1.f, ty, tx);
    }
}

// Fallback (if 160 KiB dynamic LDS unavailable): r10 proj, 288 blocks.
__global__ __launch_bounds__(512) void proj_kernel(
    const ushort* __restrict__ xb, const ushort* __restrict__ Wt,
    ushort* __restrict__ Qb, ushort* __restrict__ Kb,
    ushort* __restrict__ Vt, float qscale) {
    extern __shared__ ushort sm[];
    const int b0 = blockIdx.x;                      // 288 = 8 XCD x 36
    const int i = b0 & 7, j = b0 >> 3;
    int z, ty, tx;
    if (j < 12) {
        z = 2; ty = i * 4 + j / 3; tx = j % 3;
    } else {
        int j2 = j - 12;
        z = j2 / 12;
        int j3 = j2 % 12;
        ty = i * 4 + j3 / 3; tx = j3 % 3;
    }
    if (z == 0)
        gemmN<0, 4>(sm, xb, D_, Wt, D_, Qb, U_, D_, qscale, ty, tx);
    else if (z == 1)
        gemmN<0, 4>(sm, xb, D_, Wt + (size_t)U_ * D_, D_, Kb, U_, D_, 1.f, ty, tx);
    else
        gemmN<1, 4>(sm, xb, D_, Wt + (size_t)2 * U_ * D_, D_, Vt, 0, D_, 1.f, ty, tx);
}

// scores -> bf16 (scale folded into Q). 256 blocks, 8-phase.
__global__ __launch_bounds__(512) void scores_kernel(
    const ushort* __restrict__ Qb, const ushort* __restrict__ Kb,
    ushort* __restrict__ Sc) {
    extern __shared__ ushort sm[];
    const int nwg = gridDim.x;                       // 256 or 64, %8==0
    const int b0 = blockIdx.x;
    const int wg = (b0 & 7) * (nwg >> 3) + (b0 >> 3);
    const int tx = wg & 7, ty = (wg >> 3) & 7, z = wg >> 6;
    gemmN<0, 4>(sm, Qb + (size_t)z * S_ * U_, U_, Kb + (size_t)z * S_ * U_, U_,
                Sc + (size_t)z * S_ * S_, S_, U_, 1.f, ty, tx);
}

// PV split-K=2: 192 blocks; both halves emit BF16 partials (p0, p1).
__global__ __launch_bounds__(512) void pv_split_kernel(
    const ushort* __restrict__ P, const ushort* __restrict__ Vt,
    ushort* __restrict__ p0, ushort* __restrict__ p1) {
    extern __shared__ ushort sm[];
    const int b0 = blockIdx.x;                      // 192 = 8 XCD x 24
    const int wg = (b0 & 7) * 24 + (b0 >> 3);
    const int zk = wg / 24, rem = wg % 24;
    const int z = zk >> 1, kc = zk & 1;
    const int ty = rem / 3, tx = rem % 3;
    ushort* dst = (kc ? p1 : p0) + (size_t)z * S_ * U_;
    gemmN<0, 4>(sm, P + (size_t)z * S_ * S_ + kc * 1024, S_,
                Vt + (size_t)z * U_ * S_ + kc * 1024, S_,
                dst, U_, 1024, 1.f, ty, tx);
}

// out = f32(p0) + f32(p1)  (bf16 partials -> 50.4 MB traffic)
__global__ void reduce_bf_kernel(float4* __restrict__ out,
                                 const uint4* __restrict__ p0,
                                 const uint4* __restrict__ p1, int n8) {
    int i = blockIdx.x * 256 + threadIdx.x;
    const int stride = gridDim.x * 256;
    for (; i < n8; i += stride) {
        uint4 a = p0[i], b = p1[i];
        float4 o0, o1;
        o0.x = bflo(a.x) + bflo(b.x); o0.y = bfhi(a.x) + bfhi(b.x);
        o0.z = bflo(a.y) + bflo(b.y); o0.w = bfhi(a.y) + bfhi(b.y);
        o1.x = bflo(a.z) + bflo(b.z); o1.y = bfhi(a.z) + bfhi(b.z);
        o1.z = bflo(a.w) + bflo(b.w); o1.w = bfhi(a.w) + bfhi(b.w);
        out[2 * i] = o0;
        out[2 * i + 1] = o1;
    }
}

// PV without split (fallback when ws lacks the full Sc region). 96 blocks.
__global__ __launch_bounds__(512) void pv_kernel(
    const ushort* __restrict__ P, const ushort* __restrict__ Vt,
    float* __restrict__ out) {
    extern __shared__ ushort sm[];
    const int b0 = blockIdx.x;                      // 96 = 8 XCD x 12
    const int wg = (b0 & 7) * 12 + (b0 >> 3);
    const int z = wg / 24, rem = wg % 24;
    const int ty = rem / 3, tx = rem % 3;
    gemmN<2, 4>(sm, P + (size_t)z * S_ * S_, S_, Vt + (size_t)z * U_ * S_, S_,
                out + (size_t)z * S_ * U_, U_, S_, 1.f, ty, tx);
}

// ======================= small helper kernels ========================

// Merged input prep: blocks [0,6144) cast x -> bf16; blocks [6144,7872)
// transpose W{q,k,v} -> Wt bf16 [z][U][D]. Branch is block-uniform.
__global__ __launch_bounds__(256) void prep_kernel(
    const float* __restrict__ x,
    const float* __restrict__ Wq, const float* __restrict__ Wk,
    const float* __restrict__ Wv,
    ushort* __restrict__ xb, ushort* __restrict__ Wt) {
    __shared__ float tsh[32][33];
    const int bid = blockIdx.x, tid = threadIdx.x;
    if (bid < 6144) {
        int i = bid * 256 + tid;                    // n4 = 6144*256 exactly
        float4 v = ((const float4*)x)[i];
        ushort4 o;
        o.x = f2bf(v.x); o.y = f2bf(v.y); o.z = f2bf(v.z); o.w = f2bf(v.w);
        ((ushort4*)xb)[i] = o;
    } else {
        int b2 = bid - 6144;
        int zz = b2 / 576, rem = b2 % 576;
        int by = rem / 24, bx = rem % 24;
        const float* W = zz == 0 ? Wq : (zz == 1 ? Wk : Wv);
        int x0 = bx * 32, y0 = by * 32;
        int txx = tid & 31, tyy = tid >> 5;         // 32 x 8
        for (int i = tyy; i < 32; i += 8)
            tsh[i][txx] = W[(size_t)(y0 + i) * U_ + (x0 + txx)];
        __syncthreads();
        ushort* Wtz = Wt + (size_t)zz * U_ * D_;
        for (int i = tyy; i < 32; i += 8)
            Wtz[(size_t)(x0 + i) * D_ + (y0 + txx)] = f2bf(tsh[txx][i]);
    }
}

// Row softmax over bf16 scores -> bf16 P. One row per block.
__global__ __launch_bounds__(256) void softmax_kernel(
    const ushort* __restrict__ Sc, ushort* __restrict__ P) {
    size_t row = (size_t)blockIdx.y * gridDim.x + blockIdx.x;
    const uint4* r4 = (const uint4*)(Sc + row * S_);
    int t = threadIdx.x;
    int w = t >> 6, l = t & 63;
    uint4 a = r4[t];
    float e[8];
    e[0] = bflo(a.x); e[1] = bfhi(a.x);
    e[2] = bflo(a.y); e[3] = bfhi(a.y);
    e[4] = bflo(a.z); e[5] = bfhi(a.z);
    e[6] = bflo(a.w); e[7] = bfhi(a.w);
    float mx = fmaxf(fmaxf(fmaxf(e[0], e[1]), fmaxf(e[2], e[3])),
                     fmaxf(fmaxf(e[4], e[5]), fmaxf(e[6], e[7])));
#pragma unroll
    for (int off = 32; off; off >>= 1) mx = fmaxf(mx, __shfl_xor(mx, off));
    __shared__ float red[8];
    if (l == 0) red[w] = mx;
    __syncthreads();
    mx = fmaxf(fmaxf(red[0], red[1]), fmaxf(red[2], red[3]));
    float s = 0.f;
#pragma unroll
    for (int i = 0; i < 8; ++i) { e[i] = __expf(e[i] - mx); s += e[i]; }
#pragma unroll
    for (int off = 32; off; off >>= 1) s += __shfl_xor(s, off);
    if (l == 0) red[4 + w] = s;
    __syncthreads();
    float inv = 1.f / (red[4] + red[5] + red[6] + red[7]);
    uint4 o;
    o.x = (uint32_t)f2bf(e[0] * inv) | ((uint32_t)f2bf(e[1] * inv) << 16);
    o.y = (uint32_t)f2bf(e[2] * inv) | ((uint32_t)f2bf(e[3] * inv) << 16);
    o.z = (uint32_t)f2bf(e[4] * inv) | ((uint32_t)f2bf(e[5] * inv) << 16);
    o.w = (uint32_t)f2bf(e[6] * inv) | ((uint32_t)f2bf(e[7] * inv) << 16);
    ((uint4*)(P + row * S_))[t] = o;
}

extern "C" void kernel_launch(void* const* d_in, const int* in_sizes, int n_in,
                              void* d_out, int out_size, void* d_ws, size_t ws_size,
                              hipStream_t stream) {
    (void)in_sizes; (void)n_in; (void)out_size;
    const float* x = (const float*)d_in[0];
    const float* Wq = (const float*)d_in[1];
    const float* Wk = (const float*)d_in[2];
    const float* Wv = (const float*)d_in[3];
    float* out = (float*)d_out;

    char* ws = (char*)d_ws;
    size_t off = 0;
    auto alloc = [&](size_t bytes) -> void* {
        void* p = ws + off;
        off += (bytes + 255) & ~(size_t)255;
        return p;
    };
    ushort* xb = (ushort*)alloc((size_t)B_ * S_ * D_ * 2);
    ushort* Wt = (ushort*)alloc((size_t)3 * U_ * D_ * 2);
    ushort* Qb = (ushort*)alloc((size_t)B_ * S_ * U_ * 2);
    ushort* Kb = (ushort*)alloc((size_t)B_ * S_ * U_ * 2);
    ushort* Vt = (ushort*)alloc((size_t)B_ * S_ * U_ * 2);  // [B][U][S]
    ushort* P  = (ushort*)alloc((size_t)B_ * S_ * S_ * 2);
    bool full = (ws_size - off) >= (size_t)B_ * S_ * S_ * 2 + 256;
    ushort* Sc = (ushort*)alloc(full ? (size_t)B_ * S_ * S_ * 2 : (size_t)S_ * S_ * 2);

    bool big = hipFuncSetAttribute(
                   reinterpret_cast<const void*>(proj_mix_kernel),
                   hipFuncAttributeMaxDynamicSharedMemorySize, 163840) ==
               hipSuccess;
    hipFuncSetAttribute(reinterpret_cast<const void*>(proj_kernel),
                        hipFuncAttributeMaxDynamicSharedMemorySize, 135168);
    hipFuncSetAttribute(reinterpret_cast<const void*>(scores_kernel),
                        hipFuncAttributeMaxDynamicSharedMemorySize, 131072);
    hipFuncSetAttribute(reinterpret_cast<const void*>(pv_split_kernel),
                        hipFuncAttributeMaxDynamicSharedMemorySize, 131072);
    hipFuncSetAttribute(reinterpret_cast<const void*>(pv_kernel),
                        hipFuncAttributeMaxDynamicSharedMemorySize, 131072);

    const float scale = 0.036084391824351615f;  // 1/sqrt(768), folded into Q
    prep_kernel<<<7872, 256, 0, stream>>>(x, Wq, Wk, Wv, xb, Wt);
    if (big)
        proj_mix_kernel<<<224, 512, 163840, stream>>>(xb, Wt, Qb, Kb, Vt, scale);
    else
        proj_kernel<<<288, 512, 132096, stream>>>(xb, Wt, Qb, Kb, Vt, scale);

    if (full) {
        scores_kernel<<<256, 512, 131072, stream>>>(Qb, Kb, Sc);
        softmax_kernel<<<dim3(S_, B_), 256, 0, stream>>>(Sc, P);
        // Sc (33.6 MB) is dead after softmax: reuse for the two bf16 partials
        // (2 x 12.6 MB).
        ushort* p0 = Sc;
        ushort* p1 = Sc + (size_t)B_ * S_ * U_;
        pv_split_kernel<<<192, 512, 131072, stream>>>(P, Vt, p0, p1);
        reduce_bf_kernel<<<1536, 256, 0, stream>>>(
            (float4*)out, (const uint4*)p0, (const uint4*)p1, B_ * S_ * U_ / 8);
    } else {
        for (int b = 0; b < B_; ++b) {
            scores_kernel<<<64, 512, 131072, stream>>>(
                Qb + (size_t)b * S_ * U_, Kb + (size_t)b * S_ * U_, Sc);
            softmax_kernel<<<dim3(S_, 1), 256, 0, stream>>>(
                Sc, P + (size_t)b * S_ * S_);
        }
        pv_kernel<<<96, 512, 131072, stream>>>(P, Vt, out);
    }
}

// Round 12
// 135.415 us; speedup vs baseline: 1.3709x; 1.3709x over previous
//
#include <hip/hip_runtime.h>
#include <stdint.h>

#define B_ 4
#define S_ 2048
#define D_ 768
#define U_ 768

typedef __bf16 bf16x8 __attribute__((ext_vector_type(8)));
typedef float f32x4 __attribute__((ext_vector_type(4)));

#define AS1 __attribute__((address_space(1)))
#define AS3 __attribute__((address_space(3)))

#define BAR() __builtin_amdgcn_s_barrier()
#define WAITV6() asm volatile("s_waitcnt vmcnt(6)" ::: "memory")
#define WAITV0() asm volatile("s_waitcnt vmcnt(0)" ::: "memory")
#define PRIO(x) __builtin_amdgcn_s_setprio(x)

__device__ __forceinline__ ushort f2bf(float f) {
    union { float f; uint32_t u; } v; v.f = f;
    uint32_t r = v.u + 0x7fffu + ((v.u >> 16) & 1u);
    return (ushort)(r >> 16);
}

__device__ __forceinline__ float bflo(uint32_t u) {
    union { uint32_t u; float f; } v; v.u = u << 16; return v.f;
}
__device__ __forceinline__ float bfhi(uint32_t u) {
    union { uint32_t u; float f; } v; v.u = u & 0xffff0000u; return v.f;
}

__device__ __forceinline__ void gload_lds16(const void* gp, void* lp) {
    // width-16 global->LDS: HW scatters to (wave-uniform lds base) + lane*16
    __builtin_amdgcn_global_load_lds((AS1 void*)gp, (AS3 void*)lp, 16, 0, 0);
}

// ============================================================================
// 256x256 8-phase pipelined GEMM (BK=64, 8 waves 2Mx4N, counted vmcnt(6),
// XOR-swizzled LDS — conflicts measured 0, setprio around MFMA).
// C = A[M,K] @ Bt[N,K]^T.
// MODE 0: bf16 row-major out (value*scale).
// MODE 1: bf16 -> Vt[B][U][S] via LDS-transposed COALESCED stores (sm reused
//         post-loop as a [256 col][129 dword] transpose buffer; 132096 B).
// MODE 2: f32 * scale.
// NOTE (r11 lesson): per-wave acc footprint is capped at 128x64 f32 = 128
// VGPR at 8 waves/block (256 VGPR/wave HW ceiling) — BN>256 spills.
// GEMM LDS: sA[2][256*64] + sB[2][256*64] bf16 = 128 KiB dynamic.
// ============================================================================
template <int MODE>
__device__ __forceinline__ void gemm256(
    ushort* sm,
    const ushort* __restrict__ Ag, int lda,
    const ushort* __restrict__ Btg, int ldb,
    void* __restrict__ Cp, int ldc, int Kd, float scale,
    int ty, int tx)
{
    constexpr int ABUF = 256 * 64;
    ushort* sA = sm;
    ushort* sB = sm + 2 * ABUF;

    const int tid = threadIdx.x;
    const int l = tid & 63, w = tid >> 6;
    const int lr = l & 15, lg = l >> 4;
    const int wm = w >> 2, wn = w & 3;
    const int M0 = ty * 256, N0 = tx * 256;

    f32x4 acc[8][4];
#pragma unroll
    for (int m = 0; m < 8; ++m)
#pragma unroll
        for (int n = 0; n < 4; ++n)
            acc[m][n] = (f32x4){0.f, 0.f, 0.f, 0.f};

    const int NT = Kd >> 6;

    auto STA = [&](int buf, int qp, int kt) {
#pragma unroll
        for (int j = 0; j < 2; ++j) {
            int q = qp + j;
            int r0 = (w < 4) ? (q * 32 + w * 8) : (128 + q * 32 + (w - 4) * 8);
            int r = r0 + (l >> 3);
            int lc = ((l & 7) * 16) ^ ((r & 7) << 4);
            gload_lds16(Ag + (size_t)(M0 + r) * lda + kt * 64 + (lc >> 1),
                        sA + buf * ABUF + r0 * 64);
        }
    };
    auto STB = [&](int buf, int h, int kt) {
#pragma unroll
        for (int j = 0; j < 2; ++j) {
            int r0 = h * 128 + j * 64 + w * 8;
            int r = r0 + (l >> 3);
            int lc = ((l & 7) * 16) ^ ((r & 7) << 4);
            gload_lds16(Btg + (size_t)(N0 + r) * ldb + kt * 64 + (lc >> 1),
                        sB + buf * 16384 + r0 * 64);
        }
    };

    bf16x8 afr[2][2], bfr[4][2];
    auto LDB = [&](int buf) {
#pragma unroll
        for (int nf = 0; nf < 4; ++nf)
#pragma unroll
            for (int ks = 0; ks < 2; ++ks) {
                int r = wn * 64 + nf * 16 + lr;
                int off = r * 128 + ((ks * 64 + lg * 16) ^ ((r & 7) << 4));
                bfr[nf][ks] = *(const bf16x8*)((const char*)(sB + buf * 16384) + off);
            }
    };
    auto LDA = [&](int buf, int q) {
#pragma unroll
        for (int j = 0; j < 2; ++j)
#pragma unroll
            for (int ks = 0; ks < 2; ++ks) {
                int r = wm * 128 + (2 * q + j) * 16 + lr;
                int off = r * 128 + ((ks * 64 + lg * 16) ^ ((r & 7) << 4));
                afr[j][ks] = *(const bf16x8*)((const char*)(sA + buf * ABUF) + off);
            }
    };

#define MMQ(Q)                                                                 \
    PRIO(1);                                                                   \
    _Pragma("unroll")                                                          \
    for (int j = 0; j < 2; ++j)                                                \
        _Pragma("unroll")                                                      \
        for (int nf = 0; nf < 4; ++nf)                                         \
            _Pragma("unroll")                                                  \
            for (int ks = 0; ks < 2; ++ks)                                     \
                acc[2 * (Q) + j][nf] = __builtin_amdgcn_mfma_f32_16x16x32_bf16(\
                    afr[j][ks], bfr[nf][ks], acc[2 * (Q) + j][nf], 0, 0, 0);   \
    PRIO(0);

    STA(0, 0, 0); STA(0, 2, 0); STB(0, 0, 0); STB(0, 1, 0);
    if (NT > 1) {
        STB(1, 0, 1); STB(1, 1, 1); STA(1, 0, 1);
        WAITV6();
    } else {
        WAITV0();
    }
    BAR();

    for (int t = 0; t < NT; ++t) {
        const int c = t & 1;
        LDB(c); LDA(c, 0);
        if (t + 1 < NT) STA(c ^ 1, 2, t + 1);
        BAR();
        MMQ(0);
        BAR();
        LDA(c, 1);
        if (t + 2 < NT) STB(c, 0, t + 2);
        BAR();
        MMQ(1);
        BAR();
        LDA(c, 2);
        if (t + 2 < NT) STB(c, 1, t + 2);
        BAR();
        MMQ(2);
        BAR();
        LDA(c, 3);
        if (t + 2 < NT) STA(c, 0, t + 2);
        BAR();
        MMQ(3);
        if (t + 2 < NT) { WAITV6(); } else { WAITV0(); }
        BAR();
    }
#undef MMQ

    if constexpr (MODE == 1) {
        // ---- LDS-transposed Vt epilogue (coalesced stores) ----
        // sm reused as [256 col][129 dword] buffer (stride 129 => bank rotate).
        __syncthreads();               // all GEMM LDS reads complete
        uint32_t* smw = (uint32_t*)sm;
#pragma unroll
        for (int mf = 0; mf < 8; ++mf) {
#pragma unroll
            for (int nf = 0; nf < 4; ++nf) {
                int cc = wn * 64 + nf * 16 + lr;          // local col (u)
                int r0 = wm * 128 + mf * 16 + lg * 4;     // local row, mult 4
                uint32_t d0 = (uint32_t)f2bf(acc[mf][nf][0]) |
                              ((uint32_t)f2bf(acc[mf][nf][1]) << 16);
                uint32_t d1 = (uint32_t)f2bf(acc[mf][nf][2]) |
                              ((uint32_t)f2bf(acc[mf][nf][3]) << 16);
                smw[cc * 129 + (r0 >> 1)] = d0;
                smw[cc * 129 + (r0 >> 1) + 1] = d1;
            }
        }
        __syncthreads();
        // read row-linear, store contiguous: lane covers consecutive s.
        const int bb = M0 >> 11;                          // batch (no straddle)
        const int s0 = M0 & 2047;
        const int kd = tid & 127;                         // dword within row
        int u = tid >> 7;                                 // 0..3 start row
#pragma unroll
        for (int it = 0; it < 64; ++it) {
            uint32_t d = smw[u * 129 + kd];
            uint32_t* vrow = (uint32_t*)((ushort*)Cp +
                ((size_t)(bb * U_ + N0 + u)) * S_ + s0);
            vrow[kd] = d;
            u += 4;
        }
        return;
    }

    // epilogue: C/D frag mapping col = lane&15, row = (lane>>4)*4 + i
#pragma unroll
    for (int mf = 0; mf < 8; ++mf) {
#pragma unroll
        for (int nf = 0; nf < 4; ++nf) {
#pragma unroll
            for (int i = 0; i < 4; ++i) {
                int r = M0 + wm * 128 + mf * 16 + lg * 4 + i;
                int c = N0 + wn * 64 + nf * 16 + lr;
                float v = acc[mf][nf][i];
                if constexpr (MODE == 0) {
                    ((ushort*)Cp)[(size_t)r * ldc + c] = f2bf(v * scale);
                } else {
                    ((float*)Cp)[(size_t)r * ldc + c] = v * scale;
                }
            }
        }
    }
}

// Merged QKV projection: 288 blocks = 2 dispatch rounds. z=2 (Vt, heavier
// epilogue) blocks are ordered FIRST within each XCD chunk so round 2
// (last 32 blocks) contains only light Q/K blocks.
__global__ __launch_bounds__(512) void proj_kernel(
    const ushort* __restrict__ xb, const ushort* __restrict__ Wt,
    ushort* __restrict__ Qb, ushort* __restrict__ Kb,
    ushort* __restrict__ Vt, float qscale) {
    extern __shared__ ushort sm[];
    const int b0 = blockIdx.x;                      // 288 = 8 XCD x 36
    const int i = b0 & 7, j = b0 >> 3;              // XCD chunk, order in chunk
    int z, ty, tx;
    if (j < 12) {                                   // dispatched first: V
        z = 2; ty = i * 4 + j / 3; tx = j % 3;
    } else {
        int j2 = j - 12;
        z = j2 / 12;                                // 0 then 1
        int j3 = j2 % 12;
        ty = i * 4 + j3 / 3; tx = j3 % 3;
    }
    if (z == 0)
        gemm256<0>(sm, xb, D_, Wt, D_, Qb, U_, D_, qscale, ty, tx);
    else if (z == 1)
        gemm256<0>(sm, xb, D_, Wt + (size_t)U_ * D_, D_, Kb, U_, D_, 1.f, ty, tx);
    else
        gemm256<1>(sm, xb, D_, Wt + (size_t)2 * U_ * D_, D_, Vt, 0, D_, 1.f, ty, tx);
}

// scores -> bf16 (scale folded into Q). 256 blocks, 8-phase.
__global__ __launch_bounds__(512) void scores_kernel(
    const ushort* __restrict__ Qb, const ushort* __restrict__ Kb,
    ushort* __restrict__ Sc) {
    extern __shared__ ushort sm[];
    const int nwg = gridDim.x;                       // 256 or 64, %8==0
    const int b0 = blockIdx.x;
    const int wg = (b0 & 7) * (nwg >> 3) + (b0 >> 3);
    const int tx = wg & 7, ty = (wg >> 3) & 7, z = wg >> 6;
    gemm256<0>(sm, Qb + (size_t)z * S_ * U_, U_, Kb + (size_t)z * S_ * U_, U_,
               Sc + (size_t)z * S_ * S_, S_, U_, 1.f, ty, tx);
}

// PV split-K=2: 192 blocks; both halves emit BF16 partials (p0, p1).
__global__ __launch_bounds__(512) void pv_split_kernel(
    const ushort* __restrict__ P, const ushort* __restrict__ Vt,
    ushort* __restrict__ p0, ushort* __restrict__ p1) {
    extern __shared__ ushort sm[];
    const int b0 = blockIdx.x;                      // 192 = 8 XCD x 24
    const int wg = (b0 & 7) * 24 + (b0 >> 3);
    const int zk = wg / 24, rem = wg % 24;
    const int z = zk >> 1, kc = zk & 1;
    const int ty = rem / 3, tx = rem % 3;
    ushort* dst = (kc ? p1 : p0) + (size_t)z * S_ * U_;
    gemm256<0>(sm, P + (size_t)z * S_ * S_ + kc * 1024, S_,
               Vt + (size_t)z * U_ * S_ + kc * 1024, S_,
               dst, U_, 1024, 1.f, ty, tx);
}

// out = f32(p0) + f32(p1)  (bf16 partials -> 50.4 MB traffic)
__global__ void reduce_bf_kernel(float4* __restrict__ out,
                                 const uint4* __restrict__ p0,
                                 const uint4* __restrict__ p1, int n8) {
    int i = blockIdx.x * 256 + threadIdx.x;
    const int stride = gridDim.x * 256;
    for (; i < n8; i += stride) {
        uint4 a = p0[i], b = p1[i];
        float4 o0, o1;
        o0.x = bflo(a.x) + bflo(b.x); o0.y = bfhi(a.x) + bfhi(b.x);
        o0.z = bflo(a.y) + bflo(b.y); o0.w = bfhi(a.y) + bfhi(b.y);
        o1.x = bflo(a.z) + bflo(b.z); o1.y = bfhi(a.z) + bfhi(b.z);
        o1.z = bflo(a.w) + bflo(b.w); o1.w = bfhi(a.w) + bfhi(b.w);
        out[2 * i] = o0;
        out[2 * i + 1] = o1;
    }
}

// PV without split (fallback when ws lacks the full Sc region). 96 blocks.
__global__ __launch_bounds__(512) void pv_kernel(
    const ushort* __restrict__ P, const ushort* __restrict__ Vt,
    float* __restrict__ out) {
    extern __shared__ ushort sm[];
    const int b0 = blockIdx.x;                      // 96 = 8 XCD x 12
    const int wg = (b0 & 7) * 12 + (b0 >> 3);
    const int z = wg / 24, rem = wg % 24;
    const int ty = rem / 3, tx = rem % 3;
    gemm256<2>(sm, P + (size_t)z * S_ * S_, S_, Vt + (size_t)z * U_ * S_, S_,
               out + (size_t)z * S_ * U_, U_, S_, 1.f, ty, tx);
}

// ======================= small helper kernels ========================

// Merged input prep: blocks [0,6144) cast x -> bf16; blocks [6144,7872)
// transpose W{q,k,v} -> Wt bf16 [z][U][D]. Branch is block-uniform.
__global__ __launch_bounds__(256) void prep_kernel(
    const float* __restrict__ x,
    const float* __restrict__ Wq, const float* __restrict__ Wk,
    const float* __restrict__ Wv,
    ushort* __restrict__ xb, ushort* __restrict__ Wt) {
    __shared__ float tsh[32][33];
    const int bid = blockIdx.x, tid = threadIdx.x;
    if (bid < 6144) {
        int i = bid * 256 + tid;                    // n4 = 6144*256 exactly
        float4 v = ((const float4*)x)[i];
        ushort4 o;
        o.x = f2bf(v.x); o.y = f2bf(v.y); o.z = f2bf(v.z); o.w = f2bf(v.w);
        ((ushort4*)xb)[i] = o;
    } else {
        int b2 = bid - 6144;
        int zz = b2 / 576, rem = b2 % 576;
        int by = rem / 24, bx = rem % 24;
        const float* W = zz == 0 ? Wq : (zz == 1 ? Wk : Wv);
        int x0 = bx * 32, y0 = by * 32;
        int txx = tid & 31, tyy = tid >> 5;         // 32 x 8
        for (int i = tyy; i < 32; i += 8)
            tsh[i][txx] = W[(size_t)(y0 + i) * U_ + (x0 + txx)];
        __syncthreads();
        ushort* Wtz = Wt + (size_t)zz * U_ * D_;
        for (int i = tyy; i < 32; i += 8)
            Wtz[(size_t)(x0 + i) * D_ + (y0 + txx)] = f2bf(tsh[txx][i]);
    }
}

// Row softmax over bf16 scores -> bf16 P. One row per block.
__global__ __launch_bounds__(256) void softmax_kernel(
    const ushort* __restrict__ Sc, ushort* __restrict__ P) {
    size_t row = (size_t)blockIdx.y * gridDim.x + blockIdx.x;
    const uint4* r4 = (const uint4*)(Sc + row * S_);
    int t = threadIdx.x;
    int w = t >> 6, l = t & 63;
    uint4 a = r4[t];
    float e[8];
    e[0] = bflo(a.x); e[1] = bfhi(a.x);
    e[2] = bflo(a.y); e[3] = bfhi(a.y);
    e[4] = bflo(a.z); e[5] = bfhi(a.z);
    e[6] = bflo(a.w); e[7] = bfhi(a.w);
    float mx = fmaxf(fmaxf(fmaxf(e[0], e[1]), fmaxf(e[2], e[3])),
                     fmaxf(fmaxf(e[4], e[5]), fmaxf(e[6], e[7])));
#pragma unroll
    for (int off = 32; off; off >>= 1) mx = fmaxf(mx, __shfl_xor(mx, off));
    __shared__ float red[8];
    if (l == 0) red[w] = mx;
    __syncthreads();
    mx = fmaxf(fmaxf(red[0], red[1]), fmaxf(red[2], red[3]));
    float s = 0.f;
#pragma unroll
    for (int i = 0; i < 8; ++i) { e[i] = __expf(e[i] - mx); s += e[i]; }
#pragma unroll
    for (int off = 32; off; off >>= 1) s += __shfl_xor(s, off);
    if (l == 0) red[4 + w] = s;
    __syncthreads();
    float inv = 1.f / (red[4] + red[5] + red[6] + red[7]);
    uint4 o;
    o.x = (uint32_t)f2bf(e[0] * inv) | ((uint32_t)f2bf(e[1] * inv) << 16);
    o.y = (uint32_t)f2bf(e[2] * inv) | ((uint32_t)f2bf(e[3] * inv) << 16);
    o.z = (uint32_t)f2bf(e[4] * inv) | ((uint32_t)f2bf(e[5] * inv) << 16);
    o.w = (uint32_t)f2bf(e[6] * inv) | ((uint32_t)f2bf(e[7] * inv) << 16);
    ((uint4*)(P + row * S_))[t] = o;
}

extern "C" void kernel_launch(void* const* d_in, const int* in_sizes, int n_in,
                              void* d_out, int out_size, void* d_ws, size_t ws_size,
                              hipStream_t stream) {
    (void)in_sizes; (void)n_in; (void)out_size;
    const float* x = (const float*)d_in[0];
    const float* Wq = (const float*)d_in[1];
    const float* Wk = (const float*)d_in[2];
    const float* Wv = (const float*)d_in[3];
    float* out = (float*)d_out;

    char* ws = (char*)d_ws;
    size_t off = 0;
    auto alloc = [&](size_t bytes) -> void* {
        void* p = ws + off;
        off += (bytes + 255) & ~(size_t)255;
        return p;
    };
    ushort* xb = (ushort*)alloc((size_t)B_ * S_ * D_ * 2);
    ushort* Wt = (ushort*)alloc((size_t)3 * U_ * D_ * 2);
    ushort* Qb = (ushort*)alloc((size_t)B_ * S_ * U_ * 2);
    ushort* Kb = (ushort*)alloc((size_t)B_ * S_ * U_ * 2);
    ushort* Vt = (ushort*)alloc((size_t)B_ * S_ * U_ * 2);  // [B][U][S]
    ushort* P  = (ushort*)alloc((size_t)B_ * S_ * S_ * 2);
    bool full = (ws_size - off) >= (size_t)B_ * S_ * S_ * 2 + 256;
    ushort* Sc = (ushort*)alloc(full ? (size_t)B_ * S_ * S_ * 2 : (size_t)S_ * S_ * 2);

    hipFuncSetAttribute(reinterpret_cast<const void*>(proj_kernel),
                        hipFuncAttributeMaxDynamicSharedMemorySize, 135168);
    hipFuncSetAttribute(reinterpret_cast<const void*>(scores_kernel),
                        hipFuncAttributeMaxDynamicSharedMemorySize, 131072);
    hipFuncSetAttribute(reinterpret_cast<const void*>(pv_split_kernel),
                        hipFuncAttributeMaxDynamicSharedMemorySize, 131072);
    hipFuncSetAttribute(reinterpret_cast<const void*>(pv_kernel),
                        hipFuncAttributeMaxDynamicSharedMemorySize, 131072);

    const float scale = 0.036084391824351615f;  // 1/sqrt(768), folded into Q
    prep_kernel<<<7872, 256, 0, stream>>>(x, Wq, Wk, Wv, xb, Wt);
    // 132096 B dynamic LDS: max(GEMM 131072, transpose 256*129*4)
    proj_kernel<<<288, 512, 132096, stream>>>(xb, Wt, Qb, Kb, Vt, scale);

    if (full) {
        scores_kernel<<<256, 512, 131072, stream>>>(Qb, Kb, Sc);
        softmax_kernel<<<dim3(S_, B_), 256, 0, stream>>>(Sc, P);
        // Sc (33.6 MB) is dead after softmax: reuse for the two bf16 partials
        // (2 x 12.6 MB).
        ushort* p0 = Sc;
        ushort* p1 = Sc + (size_t)B_ * S_ * U_;
        pv_split_kernel<<<192, 512, 131072, stream>>>(P, Vt, p0, p1);
        reduce_bf_kernel<<<1536, 256, 0, stream>>>(
            (float4*)out, (const uint4*)p0, (const uint4*)p1, B_ * S_ * U_ / 8);
    } else {
        for (int b = 0; b < B_; ++b) {
            scores_kernel<<<64, 512, 131072, stream>>>(
                Qb + (size_t)b * S_ * U_, Kb + (size_t)b * S_ * U_, Sc);
            softmax_kernel<<<dim3(S_, 1), 256, 0, stream>>>(
                Sc, P + (size_t)b * S_ * S_);
        }
        pv_kernel<<<96, 512, 131072, stream>>>(P, Vt, out);
    }
}

// Round 13
// 132.268 us; speedup vs baseline: 1.4036x; 1.0238x over previous
//
#include <hip/hip_runtime.h>
#include <stdint.h>

#define B_ 4
#define S_ 2048
#define D_ 768
#define U_ 768

typedef __bf16 bf16x8 __attribute__((ext_vector_type(8)));
typedef float f32x4 __attribute__((ext_vector_type(4)));

#define AS1 __attribute__((address_space(1)))
#define AS3 __attribute__((address_space(3)))

#define BAR() __builtin_amdgcn_s_barrier()
#define WAITV6() asm volatile("s_waitcnt vmcnt(6)" ::: "memory")
#define WAITV5() asm volatile("s_waitcnt vmcnt(5)" ::: "memory")
#define WAITV0() asm volatile("s_waitcnt vmcnt(0)" ::: "memory")
#define PRIO(x) __builtin_amdgcn_s_setprio(x)

__device__ __forceinline__ ushort f2bf(float f) {
    union { float f; uint32_t u; } v; v.f = f;
    uint32_t r = v.u + 0x7fffu + ((v.u >> 16) & 1u);
    return (ushort)(r >> 16);
}

__device__ __forceinline__ float bflo(uint32_t u) {
    union { uint32_t u; float f; } v; v.u = u << 16; return v.f;
}
__device__ __forceinline__ float bfhi(uint32_t u) {
    union { uint32_t u; float f; } v; v.u = u & 0xffff0000u; return v.f;
}

__device__ __forceinline__ void gload_lds16(const void* gp, void* lp) {
    // width-16 global->LDS: HW scatters to (wave-uniform lds base) + lane*16
    __builtin_amdgcn_global_load_lds((AS1 void*)gp, (AS3 void*)lp, 16, 0, 0);
}

// ============================================================================
// 256 x (64*NF) 8-phase pipelined GEMM (BK=64, 8 waves 2Mx4N, counted vmcnt,
// XOR-swizzled LDS, setprio).  C = A[M,K] @ Bt[N,K]^T.  NF in {3, 4}.
// B is staged as 64-row chunks (1 gload/thread each); NF=4's chunk pairs at
// p1/p2 reproduce the proven r10 issue order bit-for-bit (vmcnt(6)).
// NF=3 (BN=192): one chunk at p1/p2/p3; tile-end vmcnt(5) — queue-simulated:
//   leaves exactly {B0,B1,B2,A01}(t+2), drains A23(t+1). acc[8][3]=96 VGPR.
// MODE 0: bf16 row-major out (value*scale).
// MODE 1 (NF=4 only): bf16 -> Vt[B][U][S] via LDS-transposed coalesced stores.
// MODE 2: f32 * scale.
// NOTE (r11 lesson): per-wave acc is capped at 128 VGPR (256/wave HW ceiling
// at 8 waves) — BN>256 spills. LDS: 64K(sA) + NF*16K(sB).
// ============================================================================
template <int MODE, int NF>
__device__ __forceinline__ void gemmN(
    ushort* sm,
    const ushort* __restrict__ Ag, int lda,
    const ushort* __restrict__ Btg, int ldb,
    void* __restrict__ Cp, int ldc, int Kd, float scale,
    int ty, int tx)
{
    constexpr int ABUF = 256 * 64;
    constexpr int BBUF = NF * 64 * 64;
    constexpr int BN = NF * 64;
    ushort* sA = sm;
    ushort* sB = sm + 2 * ABUF;

    const int tid = threadIdx.x;
    const int l = tid & 63, w = tid >> 6;
    const int lr = l & 15, lg = l >> 4;
    const int wm = w >> 2, wn = w & 3;
    const int M0 = ty * 256, N0 = tx * BN;

    f32x4 acc[8][NF];
#pragma unroll
    for (int m = 0; m < 8; ++m)
#pragma unroll
        for (int n = 0; n < NF; ++n)
            acc[m][n] = (f32x4){0.f, 0.f, 0.f, 0.f};

    const int NT = Kd >> 6;

    auto STA = [&](int buf, int qp, int kt) {
#pragma unroll
        for (int j = 0; j < 2; ++j) {
            int q = qp + j;
            int r0 = (w < 4) ? (q * 32 + w * 8) : (128 + q * 32 + (w - 4) * 8);
            int r = r0 + (l >> 3);
            int lc = ((l & 7) * 16) ^ ((r & 7) << 4);
            gload_lds16(Ag + (size_t)(M0 + r) * lda + kt * 64 + (lc >> 1),
                        sA + buf * ABUF + r0 * 64);
        }
    };
    // stage one 64-row B chunk (1 gload/thread)
    auto STB1 = [&](int buf, int h, int kt) {
        int r0 = h * 64 + w * 8;
        int r = r0 + (l >> 3);
        int lc = ((l & 7) * 16) ^ ((r & 7) << 4);
        gload_lds16(Btg + (size_t)(N0 + r) * ldb + kt * 64 + (lc >> 1),
                    sB + buf * BBUF + r0 * 64);
    };

    bf16x8 afr[2][2], bfr[NF][2];
    auto LDB = [&](int buf) {
#pragma unroll
        for (int nf = 0; nf < NF; ++nf)
#pragma unroll
            for (int ks = 0; ks < 2; ++ks) {
                int r = wn * (16 * NF) + nf * 16 + lr;
                int off = r * 128 + ((ks * 64 + lg * 16) ^ ((r & 7) << 4));
                bfr[nf][ks] = *(const bf16x8*)((const char*)(sB + buf * BBUF) + off);
            }
    };
    auto LDA = [&](int buf, int q) {
#pragma unroll
        for (int j = 0; j < 2; ++j)
#pragma unroll
            for (int ks = 0; ks < 2; ++ks) {
                int r = wm * 128 + (2 * q + j) * 16 + lr;
                int off = r * 128 + ((ks * 64 + lg * 16) ^ ((r & 7) << 4));
                afr[j][ks] = *(const bf16x8*)((const char*)(sA + buf * ABUF) + off);
            }
    };

#define MMQ(Q)                                                                 \
    PRIO(1);                                                                   \
    _Pragma("unroll")                                                          \
    for (int j = 0; j < 2; ++j)                                                \
        _Pragma("unroll")                                                      \
        for (int nf = 0; nf < NF; ++nf)                                        \
            _Pragma("unroll")                                                  \
            for (int ks = 0; ks < 2; ++ks)                                     \
                acc[2 * (Q) + j][nf] = __builtin_amdgcn_mfma_f32_16x16x32_bf16(\
                    afr[j][ks], bfr[nf][ks], acc[2 * (Q) + j][nf], 0, 0, 0);   \
    PRIO(0);

#define WAITN()                                                                \
    do { if constexpr (NF == 4) { WAITV6(); } else { WAITV5(); } } while (0)

    // prologue: tile0 fully + tile1's {all B chunks, A-q01}
    STA(0, 0, 0); STA(0, 2, 0);
#pragma unroll
    for (int h = 0; h < NF; ++h) STB1(0, h, 0);
    if (NT > 1) {
#pragma unroll
        for (int h = 0; h < NF; ++h) STB1(1, h, 1);
        STA(1, 0, 1);
        WAITN();
    } else {
        WAITV0();
    }
    BAR();

    for (int t = 0; t < NT; ++t) {
        const int c = t & 1;
        LDB(c); LDA(c, 0);
        if (t + 1 < NT) STA(c ^ 1, 2, t + 1);
        BAR();
        MMQ(0);
        BAR();
        LDA(c, 1);
        if (t + 2 < NT) {
            STB1(c, 0, t + 2);
            if constexpr (NF == 4) STB1(c, 1, t + 2);
        }
        BAR();
        MMQ(1);
        BAR();
        LDA(c, 2);
        if (t + 2 < NT) {
            if constexpr (NF == 4) { STB1(c, 2, t + 2); STB1(c, 3, t + 2); }
            else                   { STB1(c, 1, t + 2); }
        }
        BAR();
        MMQ(2);
        BAR();
        LDA(c, 3);
        if (t + 2 < NT) {
            if constexpr (NF == 3) STB1(c, 2, t + 2);
            STA(c, 0, t + 2);
        }
        BAR();
        MMQ(3);
        if (t + 2 < NT) { WAITN(); } else { WAITV0(); }
        BAR();
    }
#undef MMQ
#undef WAITN

    if constexpr (MODE == 1) {
        // ---- LDS-transposed Vt epilogue (coalesced stores), NF=4 only ----
        __syncthreads();               // all GEMM LDS reads complete
        uint32_t* smw = (uint32_t*)sm;
#pragma unroll
        for (int mf = 0; mf < 8; ++mf) {
#pragma unroll
            for (int nf = 0; nf < NF; ++nf) {
                int cc = wn * (16 * NF) + nf * 16 + lr;   // local col (u)
                int r0 = wm * 128 + mf * 16 + lg * 4;     // local row, mult 4
                uint32_t d0 = (uint32_t)f2bf(acc[mf][nf][0]) |
                              ((uint32_t)f2bf(acc[mf][nf][1]) << 16);
                uint32_t d1 = (uint32_t)f2bf(acc[mf][nf][2]) |
                              ((uint32_t)f2bf(acc[mf][nf][3]) << 16);
                smw[cc * 129 + (r0 >> 1)] = d0;
                smw[cc * 129 + (r0 >> 1) + 1] = d1;
            }
        }
        __syncthreads();
        // read row-linear, store contiguous: lane covers consecutive s.
        const int bb = M0 >> 11;                          // batch (no straddle)
        const int s0 = M0 & 2047;
        const int kd = tid & 127;                         // dword within row
        int u = tid >> 7;                                 // 0..3 start row
#pragma unroll
        for (int it = 0; it < 64; ++it) {
            uint32_t d = smw[u * 129 + kd];
            uint32_t* vrow = (uint32_t*)((ushort*)Cp +
                ((size_t)(bb * U_ + N0 + u)) * S_ + s0);
            vrow[kd] = d;
            u += 4;
        }
        return;
    }

    // epilogue: C/D frag mapping col = lane&15, row = (lane>>4)*4 + i
#pragma unroll
    for (int mf = 0; mf < 8; ++mf) {
#pragma unroll
        for (int nf = 0; nf < NF; ++nf) {
#pragma unroll
            for (int i = 0; i < 4; ++i) {
                int r = M0 + wm * 128 + mf * 16 + lg * 4 + i;
                int c = N0 + wn * (16 * NF) + nf * 16 + lr;
                float v = acc[mf][nf][i];
                if constexpr (MODE == 0) {
                    ((ushort*)Cp)[(size_t)r * ldc + c] = f2bf(v * scale);
                } else {
                    ((float*)Cp)[(size_t)r * ldc + c] = v * scale;
                }
            }
        }
    }
}

// Merged QKV projection: 288 blocks = 2 dispatch rounds. z=2 (Vt, heavier
// epilogue) blocks are ordered FIRST within each XCD chunk so round 2
// (last 32 blocks) contains only light Q/K blocks.
__global__ __launch_bounds__(512) void proj_kernel(
    const ushort* __restrict__ xb, const ushort* __restrict__ Wt,
    ushort* __restrict__ Qb, ushort* __restrict__ Kb,
    ushort* __restrict__ Vt, float qscale) {
    extern __shared__ ushort sm[];
    const int b0 = blockIdx.x;                      // 288 = 8 XCD x 36
    const int i = b0 & 7, j = b0 >> 3;              // XCD chunk, order in chunk
    int z, ty, tx;
    if (j < 12) {                                   // dispatched first: V
        z = 2; ty = i * 4 + j / 3; tx = j % 3;
    } else {
        int j2 = j - 12;
        z = j2 / 12;                                // 0 then 1
        int j3 = j2 % 12;
        ty = i * 4 + j3 / 3; tx = j3 % 3;
    }
    if (z == 0)
        gemmN<0, 4>(sm, xb, D_, Wt, D_, Qb, U_, D_, qscale, ty, tx);
    else if (z == 1)
        gemmN<0, 4>(sm, xb, D_, Wt + (size_t)U_ * D_, D_, Kb, U_, D_, 1.f, ty, tx);
    else
        gemmN<1, 4>(sm, xb, D_, Wt + (size_t)2 * U_ * D_, D_, Vt, 0, D_, 1.f, ty, tx);
}

// scores -> bf16 (scale folded into Q). 256 blocks, 8-phase.
__global__ __launch_bounds__(512) void scores_kernel(
    const ushort* __restrict__ Qb, const ushort* __restrict__ Kb,
    ushort* __restrict__ Sc) {
    extern __shared__ ushort sm[];
    const int nwg = gridDim.x;                       // 256 or 64, %8==0
    const int b0 = blockIdx.x;
    const int wg = (b0 & 7) * (nwg >> 3) + (b0 >> 3);
    const int tx = wg & 7, ty = (wg >> 3) & 7, z = wg >> 6;
    gemmN<0, 4>(sm, Qb + (size_t)z * S_ * U_, U_, Kb + (size_t)z * S_ * U_, U_,
                Sc + (size_t)z * S_ * S_, S_, U_, 1.f, ty, tx);
}

// PV split-K=2 at BN=192: 256 blocks = PERFECT 1 round (4z x 8ty x 4tx x 2kc).
// One (z,kc) per XCD: V-half (1.5 MB) L2-resident. bf16 partials p0/p1.
__global__ __launch_bounds__(512) void pv_split_kernel(
    const ushort* __restrict__ P, const ushort* __restrict__ Vt,
    ushort* __restrict__ p0, ushort* __restrict__ p1) {
    extern __shared__ ushort sm[];
    const int b0 = blockIdx.x;                      // 256 = 8 XCD x 32
    const int zk = b0 & 7;                          // one (z,kc) per XCD
    const int rem = b0 >> 3;                        // 0..31
    const int z = zk >> 1, kc = zk & 1;
    const int ty = rem >> 2, tx = rem & 3;
    ushort* dst = (kc ? p1 : p0) + (size_t)z * S_ * U_;
    gemmN<0, 3>(sm, P + (size_t)z * S_ * S_ + kc * 1024, S_,
                Vt + (size_t)z * U_ * S_ + kc * 1024, S_,
                dst, U_, 1024, 1.f, ty, tx);
}

// out = f32(p0) + f32(p1)  (bf16 partials -> 50.4 MB traffic)
__global__ void reduce_bf_kernel(float4* __restrict__ out,
                                 const uint4* __restrict__ p0,
                                 const uint4* __restrict__ p1, int n8) {
    int i = blockIdx.x * 256 + threadIdx.x;
    const int stride = gridDim.x * 256;
    for (; i < n8; i += stride) {
        uint4 a = p0[i], b = p1[i];
        float4 o0, o1;
        o0.x = bflo(a.x) + bflo(b.x); o0.y = bfhi(a.x) + bfhi(b.x);
        o0.z = bflo(a.y) + bflo(b.y); o0.w = bfhi(a.y) + bfhi(b.y);
        o1.x = bflo(a.z) + bflo(b.z); o1.y = bfhi(a.z) + bfhi(b.z);
        o1.z = bflo(a.w) + bflo(b.w); o1.w = bfhi(a.w) + bfhi(b.w);
        out[2 * i] = o0;
        out[2 * i + 1] = o1;
    }
}

// PV without split (fallback when ws lacks the full Sc region). 96 blocks.
__global__ __launch_bounds__(512) void pv_kernel(
    const ushort* __restrict__ P, const ushort* __restrict__ Vt,
    float* __restrict__ out) {
    extern __shared__ ushort sm[];
    const int b0 = blockIdx.x;                      // 96 = 8 XCD x 12
    const int wg = (b0 & 7) * 12 + (b0 >> 3);
    const int z = wg / 24, rem = wg % 24;
    const int ty = rem / 3, tx = rem % 3;
    gemmN<2, 4>(sm, P + (size_t)z * S_ * S_, S_, Vt + (size_t)z * U_ * S_, S_,
                out + (size_t)z * S_ * U_, U_, S_, 1.f, ty, tx);
}

// ======================= small helper kernels ========================

// Merged input prep: blocks [0,6144) cast x -> bf16; blocks [6144,7872)
// transpose W{q,k,v} -> Wt bf16 [z][U][D]. Branch is block-uniform.
__global__ __launch_bounds__(256) void prep_kernel(
    const float* __restrict__ x,
    const float* __restrict__ Wq, const float* __restrict__ Wk,
    const float* __restrict__ Wv,
    ushort* __restrict__ xb, ushort* __restrict__ Wt) {
    __shared__ float tsh[32][33];
    const int bid = blockIdx.x, tid = threadIdx.x;
    if (bid < 6144) {
        int i = bid * 256 + tid;                    // n4 = 6144*256 exactly
        float4 v = ((const float4*)x)[i];
        ushort4 o;
        o.x = f2bf(v.x); o.y = f2bf(v.y); o.z = f2bf(v.z); o.w = f2bf(v.w);
        ((ushort4*)xb)[i] = o;
    } else {
        int b2 = bid - 6144;
        int zz = b2 / 576, rem = b2 % 576;
        int by = rem / 24, bx = rem % 24;
        const float* W = zz == 0 ? Wq : (zz == 1 ? Wk : Wv);
        int x0 = bx * 32, y0 = by * 32;
        int txx = tid & 31, tyy = tid >> 5;         // 32 x 8
        for (int i = tyy; i < 32; i += 8)
            tsh[i][txx] = W[(size_t)(y0 + i) * U_ + (x0 + txx)];
        __syncthreads();
        ushort* Wtz = Wt + (size_t)zz * U_ * D_;
        for (int i = tyy; i < 32; i += 8)
            Wtz[(size_t)(x0 + i) * D_ + (y0 + txx)] = f2bf(tsh[txx][i]);
    }
}

// Row softmax over bf16 scores -> bf16 P. One row per block.
__global__ __launch_bounds__(256) void softmax_kernel(
    const ushort* __restrict__ Sc, ushort* __restrict__ P) {
    size_t row = (size_t)blockIdx.y * gridDim.x + blockIdx.x;
    const uint4* r4 = (const uint4*)(Sc + row * S_);
    int t = threadIdx.x;
    int w = t >> 6, l = t & 63;
    uint4 a = r4[t];
    float e[8];
    e[0] = bflo(a.x); e[1] = bfhi(a.x);
    e[2] = bflo(a.y); e[3] = bfhi(a.y);
    e[4] = bflo(a.z); e[5] = bfhi(a.z);
    e[6] = bflo(a.w); e[7] = bfhi(a.w);
    float mx = fmaxf(fmaxf(fmaxf(e[0], e[1]), fmaxf(e[2], e[3])),
                     fmaxf(fmaxf(e[4], e[5]), fmaxf(e[6], e[7])));
#pragma unroll
    for (int off = 32; off; off >>= 1) mx = fmaxf(mx, __shfl_xor(mx, off));
    __shared__ float red[8];
    if (l == 0) red[w] = mx;
    __syncthreads();
    mx = fmaxf(fmaxf(red[0], red[1]), fmaxf(red[2], red[3]));
    float s = 0.f;
#pragma unroll
    for (int i = 0; i < 8; ++i) { e[i] = __expf(e[i] - mx); s += e[i]; }
#pragma unroll
    for (int off = 32; off; off >>= 1) s += __shfl_xor(s, off);
    if (l == 0) red[4 + w] = s;
    __syncthreads();
    float inv = 1.f / (red[4] + red[5] + red[6] + red[7]);
    uint4 o;
    o.x = (uint32_t)f2bf(e[0] * inv) | ((uint32_t)f2bf(e[1] * inv) << 16);
    o.y = (uint32_t)f2bf(e[2] * inv) | ((uint32_t)f2bf(e[3] * inv) << 16);
    o.z = (uint32_t)f2bf(e[4] * inv) | ((uint32_t)f2bf(e[5] * inv) << 16);
    o.w = (uint32_t)f2bf(e[6] * inv) | ((uint32_t)f2bf(e[7] * inv) << 16);
    ((uint4*)(P + row * S_))[t] = o;
}

extern "C" void kernel_launch(void* const* d_in, const int* in_sizes, int n_in,
                              void* d_out, int out_size, void* d_ws, size_t ws_size,
                              hipStream_t stream) {
    (void)in_sizes; (void)n_in; (void)out_size;
    const float* x = (const float*)d_in[0];
    const float* Wq = (const float*)d_in[1];
    const float* Wk = (const float*)d_in[2];
    const float* Wv = (const float*)d_in[3];
    float* out = (float*)d_out;

    char* ws = (char*)d_ws;
    size_t off = 0;
    auto alloc = [&](size_t bytes) -> void* {
        void* p = ws + off;
        off += (bytes + 255) & ~(size_t)255;
        return p;
    };
    ushort* xb = (ushort*)alloc((size_t)B_ * S_ * D_ * 2);
    ushort* Wt = (ushort*)alloc((size_t)3 * U_ * D_ * 2);
    ushort* Qb = (ushort*)alloc((size_t)B_ * S_ * U_ * 2);
    ushort* Kb = (ushort*)alloc((size_t)B_ * S_ * U_ * 2);
    ushort* Vt = (ushort*)alloc((size_t)B_ * S_ * U_ * 2);  // [B][U][S]
    ushort* P  = (ushort*)alloc((size_t)B_ * S_ * S_ * 2);
    bool full = (ws_size - off) >= (size_t)B_ * S_ * S_ * 2 + 256;
    ushort* Sc = (ushort*)alloc(full ? (size_t)B_ * S_ * S_ * 2 : (size_t)S_ * S_ * 2);

    hipFuncSetAttribute(reinterpret_cast<const void*>(proj_kernel),
                        hipFuncAttributeMaxDynamicSharedMemorySize, 135168);
    hipFuncSetAttribute(reinterpret_cast<const void*>(scores_kernel),
                        hipFuncAttributeMaxDynamicSharedMemorySize, 131072);
    hipFuncSetAttribute(reinterpret_cast<const void*>(pv_split_kernel),
                        hipFuncAttributeMaxDynamicSharedMemorySize, 114688);
    hipFuncSetAttribute(reinterpret_cast<const void*>(pv_kernel),
                        hipFuncAttributeMaxDynamicSharedMemorySize, 131072);

    const float scale = 0.036084391824351615f;  // 1/sqrt(768), folded into Q
    prep_kernel<<<7872, 256, 0, stream>>>(x, Wq, Wk, Wv, xb, Wt);
    // 132096 B dynamic LDS: max(GEMM 131072, transpose 256*129*4)
    proj_kernel<<<288, 512, 132096, stream>>>(xb, Wt, Qb, Kb, Vt, scale);

    if (full) {
        scores_kernel<<<256, 512, 131072, stream>>>(Qb, Kb, Sc);
        softmax_kernel<<<dim3(S_, B_), 256, 0, stream>>>(Sc, P);
        // Sc (33.6 MB) is dead after softmax: reuse for the two bf16 partials
        // (2 x 12.6 MB).
        ushort* p0 = Sc;
        ushort* p1 = Sc + (size_t)B_ * S_ * U_;
        // 114688 B dynamic LDS: sA 64K + sB 48K (NF=3)
        pv_split_kernel<<<256, 512, 114688, stream>>>(P, Vt, p0, p1);
        reduce_bf_kernel<<<1536, 256, 0, stream>>>(
            (float4*)out, (const uint4*)p0, (const uint4*)p1, B_ * S_ * U_ / 8);
    } else {
        for (int b = 0; b < B_; ++b) {
            scores_kernel<<<64, 512, 131072, stream>>>(
                Qb + (size_t)b * S_ * U_, Kb + (size_t)b * S_ * U_, Sc);
            softmax_kernel<<<dim3(S_, 1), 256, 0, stream>>>(
                Sc, P + (size_t)b * S_ * S_);
        }
        pv_kernel<<<96, 512, 131072, stream>>>(P, Vt, out);
    }
}

// Round 14
// 127.744 us; speedup vs baseline: 1.4533x; 1.0354x over previous
//
#include <hip/hip_runtime.h>
#include <stdint.h>

#define B_ 4
#define S_ 2048
#define D_ 768
#define U_ 768

typedef __bf16 bf16x8 __attribute__((ext_vector_type(8)));
typedef float f32x4 __attribute__((ext_vector_type(4)));

#define AS1 __attribute__((address_space(1)))
#define AS3 __attribute__((address_space(3)))

#define BAR() __builtin_amdgcn_s_barrier()
#define WAITV6() asm volatile("s_waitcnt vmcnt(6)" ::: "memory")
#define WAITV5() asm volatile("s_waitcnt vmcnt(5)" ::: "memory")
#define WAITV0() asm volatile("s_waitcnt vmcnt(0)" ::: "memory")
#define PRIO(x) __builtin_amdgcn_s_setprio(x)

__device__ __forceinline__ ushort f2bf(float f) {
    union { float f; uint32_t u; } v; v.f = f;
    uint32_t r = v.u + 0x7fffu + ((v.u >> 16) & 1u);
    return (ushort)(r >> 16);
}

__device__ __forceinline__ float bflo(uint32_t u) {
    union { uint32_t u; float f; } v; v.u = u << 16; return v.f;
}
__device__ __forceinline__ float bfhi(uint32_t u) {
    union { uint32_t u; float f; } v; v.u = u & 0xffff0000u; return v.f;
}

__device__ __forceinline__ void gload_lds16(const void* gp, void* lp) {
    // width-16 global->LDS: HW scatters to (wave-uniform lds base) + lane*16
    __builtin_amdgcn_global_load_lds((AS1 void*)gp, (AS3 void*)lp, 16, 0, 0);
}

// ============================================================================
// 256 x (64*NF) 8-phase pipelined GEMM (BK=64, 8 waves 2Mx4N, counted vmcnt,
// XOR-swizzled LDS, setprio).  C = A[M,K] @ Bt[N,K]^T.  NF in {3, 4}.
// B is staged as 64-row chunks (1 gload/thread each); NF=4's chunk pairs at
// p1/p2 reproduce the proven r10 issue order bit-for-bit (vmcnt(6)).
// NF=3 (BN=192): one chunk at p1/p2/p3; tile-end vmcnt(5) — queue-simulated:
//   leaves exactly {B0,B1,B2,A01}(t+2), drains A23(t+1). acc[8][3]=96 VGPR.
//   Verified bit-identical in r13 production (pv_split).
// MODE 0: bf16 row-major out (value*scale).
// MODE 1: bf16 -> Vt[B][U][S] via LDS-transposed coalesced stores
//         (transpose buffer BN x 129 dwords; fits NF=3's 112K LDS).
// MODE 2: f32 * scale.
// NOTE (r11 lesson): per-wave acc is capped at 128 VGPR (256/wave HW ceiling
// at 8 waves) — BN>256 spills. LDS: 64K(sA) + NF*16K(sB).
// ============================================================================
template <int MODE, int NF>
__device__ __forceinline__ void gemmN(
    ushort* sm,
    const ushort* __restrict__ Ag, int lda,
    const ushort* __restrict__ Btg, int ldb,
    void* __restrict__ Cp, int ldc, int Kd, float scale,
    int ty, int tx)
{
    constexpr int ABUF = 256 * 64;
    constexpr int BBUF = NF * 64 * 64;
    constexpr int BN = NF * 64;
    ushort* sA = sm;
    ushort* sB = sm + 2 * ABUF;

    const int tid = threadIdx.x;
    const int l = tid & 63, w = tid >> 6;
    const int lr = l & 15, lg = l >> 4;
    const int wm = w >> 2, wn = w & 3;
    const int M0 = ty * 256, N0 = tx * BN;

    f32x4 acc[8][NF];
#pragma unroll
    for (int m = 0; m < 8; ++m)
#pragma unroll
        for (int n = 0; n < NF; ++n)
            acc[m][n] = (f32x4){0.f, 0.f, 0.f, 0.f};

    const int NT = Kd >> 6;

    auto STA = [&](int buf, int qp, int kt) {
#pragma unroll
        for (int j = 0; j < 2; ++j) {
            int q = qp + j;
            int r0 = (w < 4) ? (q * 32 + w * 8) : (128 + q * 32 + (w - 4) * 8);
            int r = r0 + (l >> 3);
            int lc = ((l & 7) * 16) ^ ((r & 7) << 4);
            gload_lds16(Ag + (size_t)(M0 + r) * lda + kt * 64 + (lc >> 1),
                        sA + buf * ABUF + r0 * 64);
        }
    };
    // stage one 64-row B chunk (1 gload/thread)
    auto STB1 = [&](int buf, int h, int kt) {
        int r0 = h * 64 + w * 8;
        int r = r0 + (l >> 3);
        int lc = ((l & 7) * 16) ^ ((r & 7) << 4);
        gload_lds16(Btg + (size_t)(N0 + r) * ldb + kt * 64 + (lc >> 1),
                    sB + buf * BBUF + r0 * 64);
    };

    bf16x8 afr[2][2], bfr[NF][2];
    auto LDB = [&](int buf) {
#pragma unroll
        for (int nf = 0; nf < NF; ++nf)
#pragma unroll
            for (int ks = 0; ks < 2; ++ks) {
                int r = wn * (16 * NF) + nf * 16 + lr;
                int off = r * 128 + ((ks * 64 + lg * 16) ^ ((r & 7) << 4));
                bfr[nf][ks] = *(const bf16x8*)((const char*)(sB + buf * BBUF) + off);
            }
    };
    auto LDA = [&](int buf, int q) {
#pragma unroll
        for (int j = 0; j < 2; ++j)
#pragma unroll
            for (int ks = 0; ks < 2; ++ks) {
                int r = wm * 128 + (2 * q + j) * 16 + lr;
                int off = r * 128 + ((ks * 64 + lg * 16) ^ ((r & 7) << 4));
                afr[j][ks] = *(const bf16x8*)((const char*)(sA + buf * ABUF) + off);
            }
    };

#define MMQ(Q)                                                                 \
    PRIO(1);                                                                   \
    _Pragma("unroll")                                                          \
    for (int j = 0; j < 2; ++j)                                                \
        _Pragma("unroll")                                                      \
        for (int nf = 0; nf < NF; ++nf)                                        \
            _Pragma("unroll")                                                  \
            for (int ks = 0; ks < 2; ++ks)                                     \
                acc[2 * (Q) + j][nf] = __builtin_amdgcn_mfma_f32_16x16x32_bf16(\
                    afr[j][ks], bfr[nf][ks], acc[2 * (Q) + j][nf], 0, 0, 0);   \
    PRIO(0);

#define WAITN()                                                                \
    do { if constexpr (NF == 4) { WAITV6(); } else { WAITV5(); } } while (0)

    // prologue: tile0 fully + tile1's {all B chunks, A-q01}
    STA(0, 0, 0); STA(0, 2, 0);
#pragma unroll
    for (int h = 0; h < NF; ++h) STB1(0, h, 0);
    if (NT > 1) {
#pragma unroll
        for (int h = 0; h < NF; ++h) STB1(1, h, 1);
        STA(1, 0, 1);
        WAITN();
    } else {
        WAITV0();
    }
    BAR();

    for (int t = 0; t < NT; ++t) {
        const int c = t & 1;
        LDB(c); LDA(c, 0);
        if (t + 1 < NT) STA(c ^ 1, 2, t + 1);
        BAR();
        MMQ(0);
        BAR();
        LDA(c, 1);
        if (t + 2 < NT) {
            STB1(c, 0, t + 2);
            if constexpr (NF == 4) STB1(c, 1, t + 2);
        }
        BAR();
        MMQ(1);
        BAR();
        LDA(c, 2);
        if (t + 2 < NT) {
            if constexpr (NF == 4) { STB1(c, 2, t + 2); STB1(c, 3, t + 2); }
            else                   { STB1(c, 1, t + 2); }
        }
        BAR();
        MMQ(2);
        BAR();
        LDA(c, 3);
        if (t + 2 < NT) {
            if constexpr (NF == 3) STB1(c, 2, t + 2);
            STA(c, 0, t + 2);
        }
        BAR();
        MMQ(3);
        if (t + 2 < NT) { WAITN(); } else { WAITV0(); }
        BAR();
    }
#undef MMQ
#undef WAITN

    if constexpr (MODE == 1) {
        // ---- LDS-transposed Vt epilogue (coalesced stores) ----
        // sm reused as [BN col][129 dword] buffer (stride 129 => bank rotate).
        __syncthreads();               // all GEMM LDS reads complete
        uint32_t* smw = (uint32_t*)sm;
#pragma unroll
        for (int mf = 0; mf < 8; ++mf) {
#pragma unroll
            for (int nf = 0; nf < NF; ++nf) {
                int cc = wn * (16 * NF) + nf * 16 + lr;   // local col (u)
                int r0 = wm * 128 + mf * 16 + lg * 4;     // local row, mult 4
                uint32_t d0 = (uint32_t)f2bf(acc[mf][nf][0]) |
                              ((uint32_t)f2bf(acc[mf][nf][1]) << 16);
                uint32_t d1 = (uint32_t)f2bf(acc[mf][nf][2]) |
                              ((uint32_t)f2bf(acc[mf][nf][3]) << 16);
                smw[cc * 129 + (r0 >> 1)] = d0;
                smw[cc * 129 + (r0 >> 1) + 1] = d1;
            }
        }
        __syncthreads();
        // read row-linear, store contiguous: lane covers consecutive s.
        const int bb = M0 >> 11;                          // batch (no straddle)
        const int s0 = M0 & 2047;
        const int kd = tid & 127;                         // dword within row
        int u = tid >> 7;                                 // 0..3 start row
#pragma unroll
        for (int it = 0; it < 16 * NF; ++it) {
            uint32_t d = smw[u * 129 + kd];
            uint32_t* vrow = (uint32_t*)((ushort*)Cp +
                ((size_t)(bb * U_ + N0 + u)) * S_ + s0);
            vrow[kd] = d;
            u += 4;
        }
        return;
    }

    // epilogue: C/D frag mapping col = lane&15, row = (lane>>4)*4 + i
#pragma unroll
    for (int mf = 0; mf < 8; ++mf) {
#pragma unroll
        for (int nf = 0; nf < NF; ++nf) {
#pragma unroll
            for (int i = 0; i < 4; ++i) {
                int r = M0 + wm * 128 + mf * 16 + lg * 4 + i;
                int c = N0 + wn * (16 * NF) + nf * 16 + lr;
                float v = acc[mf][nf][i];
                if constexpr (MODE == 0) {
                    ((ushort*)Cp)[(size_t)r * ldc + c] = f2bf(v * scale);
                } else {
                    ((float*)Cp)[(size_t)r * ldc + c] = v * scale;
                }
            }
        }
    }
}

// ============================================================================
// Merged QKV projection at BN=192 (NF=3): 384 blocks = 8 XCD x 48 = 1.5
// rounds (vs 2 rounds at NF=4/288). Per XCD chunk: V blocks first (j<16,
// heavier epilogue), then Q (16..31), then K (32..47); each 16-block group
// is a 4ty x 4tx band so A-panels are shared within an XCD.
// ============================================================================
__global__ __launch_bounds__(512) void proj_kernel(
    const ushort* __restrict__ xb, const ushort* __restrict__ Wt,
    ushort* __restrict__ Qb, ushort* __restrict__ Kb,
    ushort* __restrict__ Vt, float qscale) {
    extern __shared__ ushort sm[];
    const int b0 = blockIdx.x;                      // 384 = 8 XCD x 48
    const int i = b0 & 7, j = b0 >> 3;              // XCD chunk, order in chunk
    const int grp = j >> 4;                         // 0: V, 1: Q, 2: K
    const int local = j & 15;
    const int ty = i * 4 + (local >> 2), tx = local & 3;
    if (grp == 0)
        gemmN<1, 3>(sm, xb, D_, Wt + (size_t)2 * U_ * D_, D_, Vt, 0, D_, 1.f, ty, tx);
    else if (grp == 1)
        gemmN<0, 3>(sm, xb, D_, Wt, D_, Qb, U_, D_, qscale, ty, tx);
    else
        gemmN<0, 3>(sm, xb, D_, Wt + (size_t)U_ * D_, D_, Kb, U_, D_, 1.f, ty, tx);
}

// scores -> bf16 (scale folded into Q). 256 blocks, 8-phase.
__global__ __launch_bounds__(512) void scores_kernel(
    const ushort* __restrict__ Qb, const ushort* __restrict__ Kb,
    ushort* __restrict__ Sc) {
    extern __shared__ ushort sm[];
    const int nwg = gridDim.x;                       // 256 or 64, %8==0
    const int b0 = blockIdx.x;
    const int wg = (b0 & 7) * (nwg >> 3) + (b0 >> 3);
    const int tx = wg & 7, ty = (wg >> 3) & 7, z = wg >> 6;
    gemmN<0, 4>(sm, Qb + (size_t)z * S_ * U_, U_, Kb + (size_t)z * S_ * U_, U_,
                Sc + (size_t)z * S_ * S_, S_, U_, 1.f, ty, tx);
}

// PV split-K=2 at BN=192: 256 blocks = PERFECT 1 round (4z x 8ty x 4tx x 2kc).
// One (z,kc) per XCD: V-half (1.5 MB) L2-resident. bf16 partials p0/p1.
__global__ __launch_bounds__(512) void pv_split_kernel(
    const ushort* __restrict__ P, const ushort* __restrict__ Vt,
    ushort* __restrict__ p0, ushort* __restrict__ p1) {
    extern __shared__ ushort sm[];
    const int b0 = blockIdx.x;                      // 256 = 8 XCD x 32
    const int zk = b0 & 7;                          // one (z,kc) per XCD
    const int rem = b0 >> 3;                        // 0..31
    const int z = zk >> 1, kc = zk & 1;
    const int ty = rem >> 2, tx = rem & 3;
    ushort* dst = (kc ? p1 : p0) + (size_t)z * S_ * U_;
    gemmN<0, 3>(sm, P + (size_t)z * S_ * S_ + kc * 1024, S_,
                Vt + (size_t)z * U_ * S_ + kc * 1024, S_,
                dst, U_, 1024, 1.f, ty, tx);
}

// out = f32(p0) + f32(p1)  (bf16 partials -> 50.4 MB traffic)
__global__ void reduce_bf_kernel(float4* __restrict__ out,
                                 const uint4* __restrict__ p0,
                                 const uint4* __restrict__ p1, int n8) {
    int i = blockIdx.x * 256 + threadIdx.x;
    const int stride = gridDim.x * 256;
    for (; i < n8; i += stride) {
        uint4 a = p0[i], b = p1[i];
        float4 o0, o1;
        o0.x = bflo(a.x) + bflo(b.x); o0.y = bfhi(a.x) + bfhi(b.x);
        o0.z = bflo(a.y) + bflo(b.y); o0.w = bfhi(a.y) + bfhi(b.y);
        o1.x = bflo(a.z) + bflo(b.z); o1.y = bfhi(a.z) + bfhi(b.z);
        o1.z = bflo(a.w) + bflo(b.w); o1.w = bfhi(a.w) + bfhi(b.w);
        out[2 * i] = o0;
        out[2 * i + 1] = o1;
    }
}

// PV without split (fallback when ws lacks the full Sc region). 96 blocks.
__global__ __launch_bounds__(512) void pv_kernel(
    const ushort* __restrict__ P, const ushort* __restrict__ Vt,
    float* __restrict__ out) {
    extern __shared__ ushort sm[];
    const int b0 = blockIdx.x;                      // 96 = 8 XCD x 12
    const int wg = (b0 & 7) * 12 + (b0 >> 3);
    const int z = wg / 24, rem = wg % 24;
    const int ty = rem / 3, tx = rem % 3;
    gemmN<2, 4>(sm, P + (size_t)z * S_ * S_, S_, Vt + (size_t)z * U_ * S_, S_,
                out + (size_t)z * S_ * U_, U_, S_, 1.f, ty, tx);
}

// ======================= small helper kernels ========================

// Merged input prep: blocks [0,6144) cast x -> bf16; blocks [6144,7872)
// transpose W{q,k,v} -> Wt bf16 [z][U][D]. Branch is block-uniform.
__global__ __launch_bounds__(256) void prep_kernel(
    const float* __restrict__ x,
    const float* __restrict__ Wq, const float* __restrict__ Wk,
    const float* __restrict__ Wv,
    ushort* __restrict__ xb, ushort* __restrict__ Wt) {
    __shared__ float tsh[32][33];
    const int bid = blockIdx.x, tid = threadIdx.x;
    if (bid < 6144) {
        int i = bid * 256 + tid;                    // n4 = 6144*256 exactly
        float4 v = ((const float4*)x)[i];
        ushort4 o;
        o.x = f2bf(v.x); o.y = f2bf(v.y); o.z = f2bf(v.z); o.w = f2bf(v.w);
        ((ushort4*)xb)[i] = o;
    } else {
        int b2 = bid - 6144;
        int zz = b2 / 576, rem = b2 % 576;
        int by = rem / 24, bx = rem % 24;
        const float* W = zz == 0 ? Wq : (zz == 1 ? Wk : Wv);
        int x0 = bx * 32, y0 = by * 32;
        int txx = tid & 31, tyy = tid >> 5;         // 32 x 8
        for (int i = tyy; i < 32; i += 8)
            tsh[i][txx] = W[(size_t)(y0 + i) * U_ + (x0 + txx)];
        __syncthreads();
        ushort* Wtz = Wt + (size_t)zz * U_ * D_;
        for (int i = tyy; i < 32; i += 8)
            Wtz[(size_t)(x0 + i) * D_ + (y0 + txx)] = f2bf(tsh[txx][i]);
    }
}

// Row softmax over bf16 scores -> bf16 P. One row per block.
__global__ __launch_bounds__(256) void softmax_kernel(
    const ushort* __restrict__ Sc, ushort* __restrict__ P) {
    size_t row = (size_t)blockIdx.y * gridDim.x + blockIdx.x;
    const uint4* r4 = (const uint4*)(Sc + row * S_);
    int t = threadIdx.x;
    int w = t >> 6, l = t & 63;
    uint4 a = r4[t];
    float e[8];
    e[0] = bflo(a.x); e[1] = bfhi(a.x);
    e[2] = bflo(a.y); e[3] = bfhi(a.y);
    e[4] = bflo(a.z); e[5] = bfhi(a.z);
    e[6] = bflo(a.w); e[7] = bfhi(a.w);
    float mx = fmaxf(fmaxf(fmaxf(e[0], e[1]), fmaxf(e[2], e[3])),
                     fmaxf(fmaxf(e[4], e[5]), fmaxf(e[6], e[7])));
#pragma unroll
    for (int off = 32; off; off >>= 1) mx = fmaxf(mx, __shfl_xor(mx, off));
    __shared__ float red[8];
    if (l == 0) red[w] = mx;
    __syncthreads();
    mx = fmaxf(fmaxf(red[0], red[1]), fmaxf(red[2], red[3]));
    float s = 0.f;
#pragma unroll
    for (int i = 0; i < 8; ++i) { e[i] = __expf(e[i] - mx); s += e[i]; }
#pragma unroll
    for (int off = 32; off; off >>= 1) s += __shfl_xor(s, off);
    if (l == 0) red[4 + w] = s;
    __syncthreads();
    float inv = 1.f / (red[4] + red[5] + red[6] + red[7]);
    uint4 o;
    o.x = (uint32_t)f2bf(e[0] * inv) | ((uint32_t)f2bf(e[1] * inv) << 16);
    o.y = (uint32_t)f2bf(e[2] * inv) | ((uint32_t)f2bf(e[3] * inv) << 16);
    o.z = (uint32_t)f2bf(e[4] * inv) | ((uint32_t)f2bf(e[5] * inv) << 16);
    o.w = (uint32_t)f2bf(e[6] * inv) | ((uint32_t)f2bf(e[7] * inv) << 16);
    ((uint4*)(P + row * S_))[t] = o;
}

extern "C" void kernel_launch(void* const* d_in, const int* in_sizes, int n_in,
                              void* d_out, int out_size, void* d_ws, size_t ws_size,
                              hipStream_t stream) {
    (void)in_sizes; (void)n_in; (void)out_size;
    const float* x = (const float*)d_in[0];
    const float* Wq = (const float*)d_in[1];
    const float* Wk = (const float*)d_in[2];
    const float* Wv = (const float*)d_in[3];
    float* out = (float*)d_out;

    char* ws = (char*)d_ws;
    size_t off = 0;
    auto alloc = [&](size_t bytes) -> void* {
        void* p = ws + off;
        off += (bytes + 255) & ~(size_t)255;
        return p;
    };
    ushort* xb = (ushort*)alloc((size_t)B_ * S_ * D_ * 2);
    ushort* Wt = (ushort*)alloc((size_t)3 * U_ * D_ * 2);
    ushort* Qb = (ushort*)alloc((size_t)B_ * S_ * U_ * 2);
    ushort* Kb = (ushort*)alloc((size_t)B_ * S_ * U_ * 2);
    ushort* Vt = (ushort*)alloc((size_t)B_ * S_ * U_ * 2);  // [B][U][S]
    ushort* P  = (ushort*)alloc((size_t)B_ * S_ * S_ * 2);
    bool full = (ws_size - off) >= (size_t)B_ * S_ * S_ * 2 + 256;
    ushort* Sc = (ushort*)alloc(full ? (size_t)B_ * S_ * S_ * 2 : (size_t)S_ * S_ * 2);

    hipFuncSetAttribute(reinterpret_cast<const void*>(proj_kernel),
                        hipFuncAttributeMaxDynamicSharedMemorySize, 114688);
    hipFuncSetAttribute(reinterpret_cast<const void*>(scores_kernel),
                        hipFuncAttributeMaxDynamicSharedMemorySize, 131072);
    hipFuncSetAttribute(reinterpret_cast<const void*>(pv_split_kernel),
                        hipFuncAttributeMaxDynamicSharedMemorySize, 114688);
    hipFuncSetAttribute(reinterpret_cast<const void*>(pv_kernel),
                        hipFuncAttributeMaxDynamicSharedMemorySize, 131072);

    const float scale = 0.036084391824351615f;  // 1/sqrt(768), folded into Q
    prep_kernel<<<7872, 256, 0, stream>>>(x, Wq, Wk, Wv, xb, Wt);
    // NF=3: 114688 B dynamic LDS (sA 64K + sB 48K; transpose 192*129*4 fits)
    proj_kernel<<<384, 512, 114688, stream>>>(xb, Wt, Qb, Kb, Vt, scale);

    if (full) {
        scores_kernel<<<256, 512, 131072, stream>>>(Qb, Kb, Sc);
        softmax_kernel<<<dim3(S_, B_), 256, 0, stream>>>(Sc, P);
        // Sc (33.6 MB) is dead after softmax: reuse for the two bf16 partials
        // (2 x 12.6 MB).
        ushort* p0 = Sc;
        ushort* p1 = Sc + (size_t)B_ * S_ * U_;
        pv_split_kernel<<<256, 512, 114688, stream>>>(P, Vt, p0, p1);
        reduce_bf_kernel<<<1536, 256, 0, stream>>>(
            (float4*)out, (const uint4*)p0, (const uint4*)p1, B_ * S_ * U_ / 8);
    } else {
        for (int b = 0; b < B_; ++b) {
            scores_kernel<<<64, 512, 131072, stream>>>(
                Qb + (size_t)b * S_ * U_, Kb + (size_t)b * S_ * U_, Sc);
            softmax_kernel<<<dim3(S_, 1), 256, 0, stream>>>(
                Sc, P + (size_t)b * S_ * S_);
        }
        pv_kernel<<<96, 512, 131072, stream>>>(P, Vt, out);
    }
}